// Round 3
// baseline (574.994 us; speedup 1.0000x reference)
//
#include <hip/hip_runtime.h>

#define D 64

typedef float f4 __attribute__((ext_vector_type(4)));

// ws layout (floats): [0,4096) = U^T, [4096,8192) = V^T, [8192,8256) = c = W@s + bias
__global__ void dmc_prep(const float* __restrict__ s,
                         const float* __restrict__ U,
                         const float* __restrict__ V,
                         const float* __restrict__ W,
                         const float* __restrict__ bias,
                         float* __restrict__ ws) {
  const int t = threadIdx.x;
  float* Ut = ws;
  float* Vt = ws + D * D;
  float* c  = ws + 2 * D * D;
  for (int idx = t; idx < D * D; idx += blockDim.x) {
    const int r = idx >> 6;
    const int col = idx & (D - 1);
    Ut[col * D + r] = U[idx];
    Vt[col * D + r] = V[idx];
  }
  if (t < D) {
    float acc = bias[t];
    #pragma unroll
    for (int k = 0; k < D; ++k) acc = fmaf(W[t * D + k], s[k], acc);
    c[t] = acc;
  }
}

// One thread per 64-dim block-row. Only pre[64] lives in registers (all
// statically indexed). h/keys are streamed as float4 chunks inside a ROLLED
// k-loop (no runtime-indexed register arrays -> no scratch). h is re-read at
// the end for the gated residual (L2 assist; out stores + keys loads are
// nontemporal to keep L2 capacity for it). U^T/V^T/s/c are wave-uniform ->
// scalar s_load operands into the fma stream.
__global__ __launch_bounds__(256, 5) void dmc_main(
    const float* __restrict__ h,
    const float* __restrict__ keys,
    const float* __restrict__ s,
    const float* __restrict__ prelu_a,
    const float* __restrict__ ws,
    float* __restrict__ out,
    const int nblocks) {
  const float* __restrict__ Ut = ws;
  const float* __restrict__ Vt = ws + D * D;
  const float* __restrict__ c  = ws + 2 * D * D;
  const float a = prelu_a[0];

  const int j = blockIdx.x * blockDim.x + threadIdx.x;
  if (j >= nblocks) return;

  const f4* __restrict__ hr4 = reinterpret_cast<const f4*>(h + (size_t)j * D);
  const f4* __restrict__ kr4 = reinterpret_cast<const f4*>(keys + (size_t)j * D);
  const f4* __restrict__ s4  = reinterpret_cast<const f4*>(s);

  float pre[D];
  #pragma unroll
  for (int i = 0; i < D; ++i) pre[i] = c[i];

  float gdot = 0.0f;

  #pragma unroll 1
  for (int q = 0; q < D / 4; ++q) {
    const f4 hq = hr4[q];
    const f4 kq = __builtin_nontemporal_load(&kr4[q]);
    const f4 sq = s4[q];
    const float* __restrict__ Uq = Ut + q * 4 * D;
    const float* __restrict__ Vq = Vt + q * 4 * D;
    #pragma unroll
    for (int kk = 0; kk < 4; ++kk) {
      const float hv = hq[kk];
      const float kv = kq[kk];
      const float sv = sq[kk];
      gdot = fmaf(hv + kv, sv, gdot);
      const float* __restrict__ ur = Uq + kk * D;
      const float* __restrict__ vr = Vq + kk * D;
      #pragma unroll
      for (int i = 0; i < D; ++i) {
        pre[i] = fmaf(hv, ur[i], fmaf(kv, vr[i], pre[i]));
      }
    }
  }

  const float g = 1.0f / (1.0f + __expf(-gdot));

  // Gated residual + norm: re-read h (recently touched; L2-assisted).
  float ss = 0.0f;
  #pragma unroll
  for (int q = 0; q < D / 4; ++q) {
    const f4 hq = hr4[q];
    #pragma unroll
    for (int kk = 0; kk < 4; ++kk) {
      const int i = 4 * q + kk;
      const float p = pre[i];
      const float act = (p >= 0.0f) ? p : a * p;
      const float hn = fmaf(g, act, hq[kk]);
      pre[i] = hn;
      ss = fmaf(hn, hn, ss);
    }
  }
  const float rn = rsqrtf(ss);

  f4* __restrict__ orow4 = reinterpret_cast<f4*>(out + (size_t)j * D);
  #pragma unroll
  for (int q = 0; q < D / 4; ++q) {
    f4 v;
    v.x = pre[4 * q + 0] * rn;
    v.y = pre[4 * q + 1] * rn;
    v.z = pre[4 * q + 2] * rn;
    v.w = pre[4 * q + 3] * rn;
    __builtin_nontemporal_store(v, &orow4[q]);
  }
}

extern "C" void kernel_launch(void* const* d_in, const int* in_sizes, int n_in,
                              void* d_out, int out_size, void* d_ws, size_t ws_size,
                              hipStream_t stream) {
  const float* s       = (const float*)d_in[0];
  const float* h       = (const float*)d_in[1];
  const float* keys    = (const float*)d_in[2];
  const float* U       = (const float*)d_in[3];
  const float* V       = (const float*)d_in[4];
  const float* W       = (const float*)d_in[5];
  const float* bias    = (const float*)d_in[6];
  const float* prelu_a = (const float*)d_in[7];
  float* out = (float*)d_out;
  float* ws  = (float*)d_ws;

  const int nblocks = in_sizes[1] / D;

  dmc_prep<<<1, 256, 0, stream>>>(s, U, V, W, bias, ws);
  const int grid = (nblocks + 255) / 256;
  dmc_main<<<grid, 256, 0, stream>>>(h, keys, s, prelu_a, ws, out, nblocks);
}

// Round 4
// 527.296 us; speedup vs baseline: 1.0905x; 1.0905x over previous
//
#include <hip/hip_runtime.h>

#define D 64

typedef float f4 __attribute__((ext_vector_type(4)));

#define REP16(X) X(0) X(1) X(2) X(3) X(4) X(5) X(6) X(7) \
                 X(8) X(9) X(10) X(11) X(12) X(13) X(14) X(15)

static __device__ __forceinline__ f4 fma4s(float a, f4 b, f4 c) {
  f4 r;
  r.x = fmaf(a, b.x, c.x);
  r.y = fmaf(a, b.y, c.y);
  r.z = fmaf(a, b.z, c.z);
  r.w = fmaf(a, b.w, c.w);
  return r;
}

static __device__ __forceinline__ f4 fma44(f4 a, f4 b, f4 c) {
  f4 r;
  r.x = fmaf(a.x, b.x, c.x);
  r.y = fmaf(a.y, b.y, c.y);
  r.z = fmaf(a.z, b.z, c.z);
  r.w = fmaf(a.w, b.w, c.w);
  return r;
}

static __device__ __forceinline__ f4 prelu4(f4 p, float a) {
  f4 r;
  r.x = p.x >= 0.0f ? p.x : a * p.x;
  r.y = p.y >= 0.0f ? p.y : a * p.y;
  r.z = p.z >= 0.0f ? p.z : a * p.z;
  r.w = p.w >= 0.0f ? p.w : a * p.w;
  return r;
}

// ws layout (floats): [0,4096) = U^T, [4096,8192) = V^T, [8192,8256) = c = W@s + bias
__global__ void dmc_prep(const float* __restrict__ s,
                         const float* __restrict__ U,
                         const float* __restrict__ V,
                         const float* __restrict__ W,
                         const float* __restrict__ bias,
                         float* __restrict__ ws) {
  const int t = threadIdx.x;
  float* Ut = ws;
  float* Vt = ws + D * D;
  float* c  = ws + 2 * D * D;
  for (int idx = t; idx < D * D; idx += blockDim.x) {
    const int r = idx >> 6;
    const int col = idx & (D - 1);
    Ut[col * D + r] = U[idx];
    Vt[col * D + r] = V[idx];
  }
  if (t < D) {
    float acc = bias[t];
    #pragma unroll
    for (int k = 0; k < D; ++k) acc = fmaf(W[t * D + k], s[k], acc);
    c[t] = acc;
  }
}

// One thread per 64-dim block-row. The 64-float accumulator is 16 NAMED f4
// variables (macro-expanded) so register promotion cannot fail (R1/R3 both
// died to array demotion -> scratch). U^T/V^T/c/s are wave-uniform -> scalar
// s_load feeding v_fma (1 SGPR operand each). h/keys stream as f4; h is
// re-read in the epilogue (L2/L3-hit) instead of being held.
__global__ __launch_bounds__(256, 3) void dmc_main(
    const float* __restrict__ h,
    const float* __restrict__ keys,
    const float* __restrict__ s,
    const float* __restrict__ prelu_a,
    const float* __restrict__ ws,
    float* __restrict__ out,
    const int nblocks) {
  const f4* __restrict__ Ut4 = reinterpret_cast<const f4*>(ws);
  const f4* __restrict__ Vt4 = reinterpret_cast<const f4*>(ws + D * D);
  const f4* __restrict__ c4  = reinterpret_cast<const f4*>(ws + 2 * D * D);
  const float a = prelu_a[0];

  const int j = blockIdx.x * blockDim.x + threadIdx.x;
  if (j >= nblocks) return;

  const f4* __restrict__ hr4 = reinterpret_cast<const f4*>(h + (size_t)j * D);
  const f4* __restrict__ kr4 = reinterpret_cast<const f4*>(keys + (size_t)j * D);
  const f4* __restrict__ s4  = reinterpret_cast<const f4*>(s);

#define DECLP(n) f4 pre##n = c4[n];
  REP16(DECLP)
#undef DECLP

  float gdot = 0.0f;

  #pragma unroll 2
  for (int q = 0; q < D / 4; ++q) {
    const f4 hq = hr4[q];
    const f4 kq = __builtin_nontemporal_load(&kr4[q]);
    const f4 sq = s4[q];
    #pragma unroll
    for (int kk = 0; kk < 4; ++kk) {
      const float hv = hq[kk];
      const float kv = kq[kk];
      gdot = fmaf(hv + kv, sq[kk], gdot);
      const f4* __restrict__ ur = Ut4 + (q * 4 + kk) * (D / 4);
      const f4* __restrict__ vr = Vt4 + (q * 4 + kk) * (D / 4);
#define STEP(n) pre##n = fma4s(hv, ur[n], fma4s(kv, vr[n], pre##n));
      REP16(STEP)
#undef STEP
    }
  }

  const float g = 1.0f / (1.0f + __expf(-gdot));

  f4 ssv = {0.0f, 0.0f, 0.0f, 0.0f};
#define EPI(n) { const f4 hq = hr4[n]; \
                 const f4 act = prelu4(pre##n, a); \
                 const f4 hn = fma4s(g, act, hq); \
                 ssv = fma44(hn, hn, ssv); \
                 pre##n = hn; }
  REP16(EPI)
#undef EPI

  const float rn = rsqrtf(ssv.x + ssv.y + ssv.z + ssv.w);

  f4* __restrict__ orow4 = reinterpret_cast<f4*>(out + (size_t)j * D);
#define STO(n) { f4 v = pre##n; \
                 v.x *= rn; v.y *= rn; v.z *= rn; v.w *= rn; \
                 __builtin_nontemporal_store(v, &orow4[n]); }
  REP16(STO)
#undef STO
}

extern "C" void kernel_launch(void* const* d_in, const int* in_sizes, int n_in,
                              void* d_out, int out_size, void* d_ws, size_t ws_size,
                              hipStream_t stream) {
  const float* s       = (const float*)d_in[0];
  const float* h       = (const float*)d_in[1];
  const float* keys    = (const float*)d_in[2];
  const float* U       = (const float*)d_in[3];
  const float* V       = (const float*)d_in[4];
  const float* W       = (const float*)d_in[5];
  const float* bias    = (const float*)d_in[6];
  const float* prelu_a = (const float*)d_in[7];
  float* out = (float*)d_out;
  float* ws  = (float*)d_ws;

  const int nblocks = in_sizes[1] / D;

  dmc_prep<<<1, 256, 0, stream>>>(s, U, V, W, bias, ws);
  const int grid = (nblocks + 255) / 256;
  dmc_main<<<grid, 256, 0, stream>>>(h, keys, s, prelu_a, ws, out, nblocks);
}